// Round 4
// baseline (349.352 us; speedup 1.0000x reference)
//
#include <hip/hip_runtime.h>
#include <hip/hip_bf16.h>
#include <math.h>

#define L_SEQ 8192
#define B_BATCH 8
#define D_DIM 256
#define BL (B_BATCH * L_SEQ)
#define EPS_F 1.1920929e-07f

typedef __attribute__((ext_vector_type(8))) short short8;
typedef __attribute__((ext_vector_type(4))) float f32x4;

// ws layout (bytes):
//   [0,       262144)  M fp32 256x256  (dead after k_packB)  ∪ starts int32 BL (k_scan+)
//   [262144,  524288)  Bpack bf16: 2 segs (M1,M2) x 8 k8 x 16 ct fragments x 64 lanes x 8
//   [524288,  589824)  hard  uint8  BL
//   [589824,  589856)  n_b   int32  8
//   [589856,  589888)  len   int32  8

__device__ inline unsigned short f2bf(float x) {
    __hip_bfloat16 b = __float2bfloat16(x);
    return *(unsigned short*)&b;
}
__device__ inline float bf2f(unsigned short u) {
    __hip_bfloat16 b = *(__hip_bfloat16*)&u;
    return __bfloat162float(b);
}

// ---------------------------------------------------------------- K1: M = Wq^T * Wk
__global__ void k_matM(const float* __restrict__ Wq, const float* __restrict__ Wk,
                       float* __restrict__ M) {
    __shared__ float Aq[16][17];
    __shared__ float Ak[16][17];
    const int tx = threadIdx.x, ty = threadIdx.y;
    const int d  = blockIdx.y * 16 + ty;   // row of M
    const int dp = blockIdx.x * 16 + tx;   // col of M
    float acc = 0.f;
    for (int e0 = 0; e0 < 256; e0 += 16) {
        Aq[ty][tx] = Wq[(e0 + ty) * 256 + blockIdx.y * 16 + tx];
        Ak[ty][tx] = Wk[(e0 + ty) * 256 + blockIdx.x * 16 + tx];
        __syncthreads();
#pragma unroll
        for (int i = 0; i < 16; ++i) acc += Aq[i][ty] * Ak[i][tx];
        __syncthreads();
    }
    M[d * 256 + dp] = acc;
}

// ------------------------- K2: pack (M - I) into bf16 hi/lo MFMA B-fragment layout
// B-frag (16x16x32 bf16): lane holds B[k = k8*32 + (lane>>4)*8 + j][n = ct*16 + (lane&15)]
// Bpack[seg][k8][ct] fragment = 64 lanes x 8 bf16 (1 KB), lane-linear (coalesced b128).
__global__ void k_packB(const float* __restrict__ M, unsigned short* __restrict__ Bpack) {
    const int f    = blockIdx.x;          // 0..255
    const int seg  = f >> 7;              // 0: hi(M1), 1: lo(M2)
    const int k8   = (f >> 4) & 7;
    const int ct   = f & 15;
    const int lane = threadIdx.x;         // 0..63
    const int q    = lane >> 4;
    const int n    = ct * 16 + (lane & 15);
    unsigned short v[8];
#pragma unroll
    for (int j = 0; j < 8; ++j) {
        const int k = k8 * 32 + q * 8 + j;
        const float Mm = M[k * 256 + n] - (k == n ? 1.0f : 0.0f);
        const unsigned short h = f2bf(Mm);
        v[j] = seg ? f2bf(Mm - bf2f(h)) : h;
    }
    unsigned short* dst = Bpack + (size_t)f * 512 + lane * 8;
#pragma unroll
    for (int j = 0; j < 8; ++j) dst[j] = v[j];
}

// ------------------------------ K3: normalize + MFMA correction GEMM + cos + hard bit
// Block = 256 thr = 4 waves, 64 output tokens [T0, T0+64). hn fp32 rows i <-> token T0-1+i.
// cos(t) = hn_{t-1}.hn_t  (exact fp32)  +  hn_{t-1}^T (M-I) hn_t  (bf16 hi/lo 3-term MFMA).
// A-fragments pre-swizzled to lane-linear LDS; V round-trips through LDS reusing h/l space.
__global__ __launch_bounds__(256, 1) void k_cosmfma(
    const float* __restrict__ hidden, const unsigned short* __restrict__ Bpack,
    const float* __restrict__ noise, unsigned char* __restrict__ hard) {
    __shared__ __attribute__((aligned(16))) float hnf[65 * 260];     // 67,600 B
    __shared__ __attribute__((aligned(16))) short frag_sh[32768];    // 65,536 B: h|l, later V

    const int tid  = threadIdx.x;
    const int lane = tid & 63;
    const int w    = tid >> 6;        // wave 0..3
    const int T0   = blockIdx.x * 64;

    // ---- stage + normalize rows, split to bf16 hi/lo A-fragments (rows 0..63) ----
    for (int i = w; i < 65; i += 4) {
        int tok = T0 - 1 + i;
        tok = tok < 0 ? 0 : tok;
        const float4 v = ((const float4*)hidden)[(size_t)tok * 64 + lane];
        float ss = v.x * v.x + v.y * v.y + v.z * v.z + v.w * v.w;
#pragma unroll
        for (int m = 32; m >= 1; m >>= 1) ss += __shfl_xor(ss, m);
        const float den = fmaxf(sqrtf(ss), 1e-12f);
        float4 h4;
        h4.x = v.x / den; h4.y = v.y / den; h4.z = v.z / den; h4.w = v.w / den;
        *(float4*)&hnf[i * 260 + lane * 4] = h4;
        if (i < 64) {
            // element cols c = 4*lane .. 4*lane+3  ->  frag coords
            const unsigned short h0 = f2bf(h4.x), h1 = f2bf(h4.y), h2 = f2bf(h4.z), h3 = f2bf(h4.w);
            const unsigned short l0 = f2bf(h4.x - bf2f(h0)), l1 = f2bf(h4.y - bf2f(h1));
            const unsigned short l2 = f2bf(h4.z - bf2f(h2)), l3 = f2bf(h4.w - bf2f(h3));
            const int tt = i >> 4, mm = i & 15;
            const int k8 = lane >> 3, qq = (lane >> 1) & 3, jh = lane & 1;
            // halfword index inside frag_sh: (((hl*4+tt)*8+k8)*64 + qq*16+mm)*8 + jh*4
            const int bi = (((tt) * 8 + k8) * 64 + qq * 16 + mm) * 8 + jh * 4;
            uint2 hw, lw;
            hw.x = (unsigned)h0 | ((unsigned)h1 << 16);
            hw.y = (unsigned)h2 | ((unsigned)h3 << 16);
            lw.x = (unsigned)l0 | ((unsigned)l1 << 16);
            lw.y = (unsigned)l2 | ((unsigned)l3 << 16);
            *(uint2*)&frag_sh[bi] = hw;
            *(uint2*)&frag_sh[16384 + bi] = lw;
        }
    }
    __syncthreads();

    // ---- K-loop: 24 steps (seg 0: h*M1, seg 1: h*M2, seg 2: l*M1), no barriers ----
    const short8* A8 = (const short8*)frag_sh;
    const short8* B8 = (const short8*)Bpack;
    f32x4 acc[16];
#pragma unroll
    for (int ct = 0; ct < 16; ++ct) { f32x4 z = {0.f, 0.f, 0.f, 0.f}; acc[ct] = z; }

#pragma unroll 2
    for (int s = 0; s < 24; ++s) {
        const int seg  = s >> 3;
        const int k8   = s & 7;
        const int hl   = (seg == 2) ? 1 : 0;
        const int bseg = (seg == 1) ? 1 : 0;
        const short8 a = A8[((hl * 4 + w) * 8 + k8) * 64 + lane];
        const short8* bp = B8 + ((bseg * 8 + k8) * 16) * 64 + lane;
        short8 bfr[16];
#pragma unroll
        for (int ct = 0; ct < 16; ++ct) bfr[ct] = bp[ct * 64];
#pragma unroll
        for (int ct = 0; ct < 16; ++ct)
            acc[ct] = __builtin_amdgcn_mfma_f32_16x16x32_bf16(a, bfr[ct], acc[ct], 0, 0, 0);
    }
    __syncthreads();   // all A-fragment reads done before overwriting with V

    // ---- V (64x256 fp32) into frag_sh region; C/D layout: col=lane&15, row=(lane>>4)*4+reg
    float* Vsh = (float*)frag_sh;
    const int m = lane & 15, q = lane >> 4;
    const int w16 = w * 16;
#pragma unroll
    for (int ct = 0; ct < 16; ++ct)
#pragma unroll
        for (int r = 0; r < 4; ++r)
            Vsh[(w16 + q * 4 + r) * 256 + ct * 16 + m] = acc[ct][r];
    // wave reads only its own V rows below -> no extra barrier needed

    // ---- epilogue: cos(t) = (hn_prev + V_prev-corr) . hn_cur, then hard decision ----
    for (int j = 0; j < 16; ++j) {
        const int rl = w16 + j;           // V row / hn prev row; token t = T0 + rl
        const float4 vv = *(const float4*)&Vsh[rl * 256 + lane * 4];
        const float4 hp = *(const float4*)&hnf[rl * 260 + lane * 4];
        const float4 hc = *(const float4*)&hnf[(rl + 1) * 260 + lane * 4];
        float part = (vv.x + hp.x) * hc.x + (vv.y + hp.y) * hc.y
                   + (vv.z + hp.z) * hc.z + (vv.w + hp.w) * hc.w;
#pragma unroll
        for (int mm = 32; mm >= 1; mm >>= 1) part += __shfl_xor(part, mm);
        if (lane == 0) {
            const int t = T0 + rl;
            const int l = t & (L_SEQ - 1);
            float p;
            if (l == 0) {
                p = 1.0f;
            } else {
                p = (1.0f - part) * 0.5f;
                p = fminf(fmaxf(p, 0.0f), 1.0f);
            }
            p = fminf(fmaxf(p, EPS_F), 1.0f - EPS_F);
            float u = noise[t];
            u = fminf(fmaxf(u, EPS_F), 1.0f - EPS_F);
            const float z = ((logf(p) - log1pf(-p)) + logf(u)) - log1pf(-u);
            hard[t] = (z > 0.0f) ? (unsigned char)1 : (unsigned char)0;
        }
    }
}

// ---------------------- K4: per-row length, forced boundary, scan -> starts, n_b, mask
__global__ void k_scan(const float* __restrict__ mask, const unsigned char* __restrict__ hard,
                       int* __restrict__ starts, int* __restrict__ nb_arr,
                       int* __restrict__ len_arr, float* __restrict__ out_short) {
    __shared__ int sc[256];
    __shared__ int s_len;
    const int b = blockIdx.x, tid = threadIdx.x;
    const int base = b * L_SEQ;

    // row length = sum(mask) (contiguous prefix of ones)
    int cnt = 0;
    const float4* m4 = (const float4*)(mask + base);
    for (int i = tid; i < L_SEQ / 4; i += 256) {
        const float4 v = m4[i];
        cnt += (v.x != 0.0f) + (v.y != 0.0f) + (v.z != 0.0f) + (v.w != 0.0f);
    }
    sc[tid] = cnt;
    __syncthreads();
    for (int ofs = 128; ofs > 0; ofs >>= 1) {
        if (tid < ofs) sc[tid] += sc[tid + ofs];
        __syncthreads();
    }
    if (tid == 0) s_len = sc[0];
    __syncthreads();
    const int len = s_len;

    // adjusted hard bits for this thread's contiguous chunk [32*tid, 32*tid+32)
    const int i0 = tid * 32;
    unsigned int bits = 0;
    int c = 0;
#pragma unroll
    for (int j = 0; j < 32; ++j) {
        const int i = i0 + j;
        int h = (i < len) ? (int)hard[base + i] : 0;
        if (len < L_SEQ && i == len - 1) h = 1;  // forced boundary at last real token
        bits |= (unsigned int)h << j;
        c += h;
    }
    __syncthreads();
    sc[tid] = c;
    __syncthreads();
    // inclusive Hillis-Steele scan over 256 thread counts
    for (int ofs = 1; ofs < 256; ofs <<= 1) {
        const int v = (tid >= ofs) ? sc[tid - ofs] : 0;
        __syncthreads();
        sc[tid] += v;
        __syncthreads();
    }
    const int off = sc[tid] - c;
    const int nb = sc[255];

    int run = off;
#pragma unroll
    for (int j = 0; j < 32; ++j)
        if ((bits >> j) & 1u) { starts[base + run] = i0 + j; ++run; }

    if (tid == 0) { nb_arr[b] = nb; len_arr[b] = len; }

    for (int i = tid; i < L_SEQ; i += 256) out_short[base + i] = (i < nb) ? 1.0f : 0.0f;
}

// --------------------------------------------- K5: one wave per segment, mean-pool
__global__ __launch_bounds__(256) void k_pool(
    const float* __restrict__ hidden, const int* __restrict__ starts,
    const int* __restrict__ nb_arr, const int* __restrict__ len_arr,
    float* __restrict__ pooled) {
    const int tid  = threadIdx.x;
    const int lane = tid & 63;
    const int wid  = blockIdx.x * 4 + (tid >> 6);
    const int b    = wid >> 13;       // / 8192
    const int s    = wid & (L_SEQ - 1);
    const int nb   = nb_arr[b];

    float4 res = {0.f, 0.f, 0.f, 0.f};
    if (s < nb) {
        const int start = (s == 0) ? 0 : starts[b * L_SEQ + s];
        const int end   = (s + 1 < nb) ? starts[b * L_SEQ + s + 1] : len_arr[b];
        float4 acc = {0.f, 0.f, 0.f, 0.f};
        for (int t = start; t < end; ++t) {
            const float4 v = ((const float4*)hidden)[(b * L_SEQ + t) * 64 + lane];
            acc.x += v.x; acc.y += v.y; acc.z += v.z; acc.w += v.w;
        }
        const float cntf = (float)(end - start);
        res.x = acc.x / cntf; res.y = acc.y / cntf; res.z = acc.z / cntf; res.w = acc.w / cntf;
    }
    ((float4*)pooled)[(size_t)wid * 64 + lane] = res;
}

// ---------------------------------------------------- K6: scalars (loss via lgamma)
__global__ void k_final(const int* __restrict__ nb_arr, const int* __restrict__ len_arr,
                        float* __restrict__ out_scal) {
    if (threadIdx.x == 0) {
        int nb = 0, ln = 0;
        for (int b = 0; b < B_BATCH; ++b) { nb += nb_arr[b]; ln += len_arr[b]; }
        const double k = (double)nb, n = (double)ln;
        const double logp = lgamma(n + 1.0) - lgamma(k + 1.0) - lgamma(n - k + 1.0)
                            + k * log(0.2) + (n - k) * log(0.8);
        const double loss = -logp / n;
        out_scal[0] = (float)loss;
        out_scal[1] = (float)nb;
        out_scal[2] = (float)ln;
    }
}

extern "C" void kernel_launch(void* const* d_in, const int* in_sizes, int n_in,
                              void* d_out, int out_size, void* d_ws, size_t ws_size,
                              hipStream_t stream) {
    const float* hidden = (const float*)d_in[0];
    const float* Wq     = (const float*)d_in[1];
    const float* Wk     = (const float*)d_in[2];
    const float* noise  = (const float*)d_in[3];
    const float* mask   = (const float*)d_in[4];
    float* out = (float*)d_out;
    char* ws = (char*)d_ws;

    float*          M      = (float*)(ws);                 // dead after k_packB
    int*            starts = (int*)(ws);                   // reuses M region (k_scan onward)
    unsigned short* Bpack  = (unsigned short*)(ws + 262144);
    unsigned char*  hard   = (unsigned char*)(ws + 524288);
    int*            nb_arr = (int*)(ws + 589824);
    int*            len_arr= (int*)(ws + 589856);

    float* pooled = out;
    float* scal   = out + (size_t)BL * D_DIM;
    float* shortm = scal + 3;

    k_matM   <<<dim3(16, 16), dim3(16, 16), 0, stream>>>(Wq, Wk, M);
    k_packB  <<<256, 64, 0, stream>>>(M, Bpack);
    k_cosmfma<<<BL / 64, 256, 0, stream>>>(hidden, Bpack, noise, hard);
    k_scan   <<<B_BATCH, 256, 0, stream>>>(mask, hard, starts, nb_arr, len_arr, shortm);
    k_pool   <<<BL / 4, 256, 0, stream>>>(hidden, starts, nb_arr, len_arr, pooled);
    k_final  <<<1, 64, 0, stream>>>(nb_arr, len_arr, scal);
}

// Round 5
// 303.120 us; speedup vs baseline: 1.1525x; 1.1525x over previous
//
#include <hip/hip_runtime.h>
#include <hip/hip_bf16.h>
#include <math.h>

#define L_SEQ 8192
#define B_BATCH 8
#define D_DIM 256
#define BL (B_BATCH * L_SEQ)
#define EPS_F 1.1920929e-07f

typedef __attribute__((ext_vector_type(8))) short short8;
typedef __attribute__((ext_vector_type(4))) float f32x4;

// ws layout (bytes):
//   [0,       262144)  M fp32 256x256  (dead after k_packB)  ∪ starts int32 BL (k_scan+)
//   [262144,  524288)  Bpack bf16: 2 segs (M1,M2) x 8 k8 x 16 ct fragments x 64 lanes x 8
//   [524288,  589824)  hard  uint8  BL
//   [589824,  589856)  n_b   int32  8
//   [589856,  589888)  len   int32  8

__device__ inline unsigned short f2bf(float x) {
    __hip_bfloat16 b = __float2bfloat16(x);
    return *(unsigned short*)&b;
}
__device__ inline float bf2f(unsigned short u) {
    __hip_bfloat16 b = *(__hip_bfloat16*)&u;
    return __bfloat162float(b);
}

// ---------------------------------------------------------------- K1: M = Wq^T * Wk
__global__ void k_matM(const float* __restrict__ Wq, const float* __restrict__ Wk,
                       float* __restrict__ M) {
    __shared__ float Aq[16][17];
    __shared__ float Ak[16][17];
    const int tx = threadIdx.x, ty = threadIdx.y;
    const int d  = blockIdx.y * 16 + ty;   // row of M
    const int dp = blockIdx.x * 16 + tx;   // col of M
    float acc = 0.f;
    for (int e0 = 0; e0 < 256; e0 += 16) {
        Aq[ty][tx] = Wq[(e0 + ty) * 256 + blockIdx.y * 16 + tx];
        Ak[ty][tx] = Wk[(e0 + ty) * 256 + blockIdx.x * 16 + tx];
        __syncthreads();
#pragma unroll
        for (int i = 0; i < 16; ++i) acc += Aq[i][ty] * Ak[i][tx];
        __syncthreads();
    }
    M[d * 256 + dp] = acc;
}

// ------------------------- K2: pack (M - I) into bf16 hi/lo MFMA B-fragment layout
// B-frag (16x16x32 bf16): lane holds B[k = k8*32 + (lane>>4)*8 + j][n = ct*16 + (lane&15)]
// Bpack[seg][k8][ct] fragment = 64 lanes x 8 bf16 (1 KB), lane-linear (coalesced b128).
__global__ void k_packB(const float* __restrict__ M, unsigned short* __restrict__ Bpack) {
    const int f    = blockIdx.x;          // 0..255
    const int seg  = f >> 7;              // 0: hi(M1), 1: lo(M2)
    const int k8   = (f >> 4) & 7;
    const int ct   = f & 15;
    const int lane = threadIdx.x;         // 0..63
    const int q    = lane >> 4;
    const int n    = ct * 16 + (lane & 15);
    unsigned short v[8];
#pragma unroll
    for (int j = 0; j < 8; ++j) {
        const int k = k8 * 32 + q * 8 + j;
        const float Mm = M[k * 256 + n] - (k == n ? 1.0f : 0.0f);
        const unsigned short h = f2bf(Mm);
        v[j] = seg ? f2bf(Mm - bf2f(h)) : h;
    }
    unsigned short* dst = Bpack + (size_t)f * 512 + lane * 8;
#pragma unroll
    for (int j = 0; j < 8; ++j) dst[j] = v[j];
}

// ------------------------------ K3: normalize + MFMA correction GEMM + cos + hard bit
// Block = 256 thr = 4 waves, 64 output tokens [T0, T0+64). hn fp32 rows i <-> token T0-1+i.
// cos(t) = hn_{t-1}.hn_t (exact fp32) + hn_{t-1}^T (M-I) hn_t (bf16 hi/lo 3-term MFMA).
// A-fragments (h,l) live in registers for the whole K-loop (built from hnf LDS once).
// K-loop: 16 global b128 B-loads (L2) + 16 MFMAs per step, no LDS, no barriers.
// Epilogue: per-wave 2-row V scratch in LDS (8 chunks), same summation order as before.
__global__ __launch_bounds__(256, 2) void k_cosmfma(
    const float* __restrict__ hidden, const unsigned short* __restrict__ Bpack,
    const float* __restrict__ noise, unsigned char* __restrict__ hard) {
    __shared__ __attribute__((aligned(16))) float hnf[65 * 260];     // 67,600 B
    __shared__ __attribute__((aligned(16))) float Vscr[4][2][256];   //  8,192 B

    const int tid  = threadIdx.x;
    const int lane = tid & 63;
    const int w    = tid >> 6;        // wave 0..3
    const int T0   = blockIdx.x * 64;

    // ---- stage + normalize 65 fp32 rows into LDS ----
    for (int i = w; i < 65; i += 4) {
        int tok = T0 - 1 + i;
        tok = tok < 0 ? 0 : tok;
        const float4 v = ((const float4*)hidden)[(size_t)tok * 64 + lane];
        float ss = v.x * v.x + v.y * v.y + v.z * v.z + v.w * v.w;
#pragma unroll
        for (int m = 32; m >= 1; m >>= 1) ss += __shfl_xor(ss, m);
        const float den = fmaxf(sqrtf(ss), 1e-12f);
        float4 h4;
        h4.x = v.x / den; h4.y = v.y / den; h4.z = v.z / den; h4.w = v.w / den;
        *(float4*)&hnf[i * 260 + lane * 4] = h4;
    }
    __syncthreads();

    // ---- build A-fragments (h, l) in registers from hnf ----
    // lane holds A[m = lane&15][k = k8*32 + (lane>>4)*8 + j], A row m <-> hnf row w*16+m
    const int m = lane & 15, q = lane >> 4;
    const int w16 = w * 16;
    short8 hA[8], lA[8];
#pragma unroll
    for (int k8 = 0; k8 < 8; ++k8) {
        const float* src = &hnf[(w16 + m) * 260 + k8 * 32 + q * 8];
        const float4 x0 = *(const float4*)src;
        const float4 x1 = *(const float4*)(src + 4);
        const float xs[8] = {x0.x, x0.y, x0.z, x0.w, x1.x, x1.y, x1.z, x1.w};
        unsigned short hh[8], ll[8];
#pragma unroll
        for (int j = 0; j < 8; ++j) {
            hh[j] = f2bf(xs[j]);
            ll[j] = f2bf(xs[j] - bf2f(hh[j]));
        }
        short8 hv, lv;
#pragma unroll
        for (int j = 0; j < 8; ++j) { hv[j] = (short)hh[j]; lv[j] = (short)ll[j]; }
        hA[k8] = hv; lA[k8] = lv;
    }

    // ---- K-loop: 24 steps (s0: h*M1, s1: h*M2, s2: l*M1) ----
    const short8* __restrict__ B8 = (const short8*)Bpack;
    f32x4 acc[16];
#pragma unroll
    for (int ct = 0; ct < 16; ++ct) { f32x4 z = {0.f, 0.f, 0.f, 0.f}; acc[ct] = z; }

#pragma unroll 2
    for (int s = 0; s < 24; ++s) {
        const int seg = s >> 3;
        const int k8  = s & 7;
        const short8 a = (seg == 2) ? lA[k8] : hA[k8];
        const short8* bp = B8 + (((seg == 1 ? 1 : 0) * 128 + k8 * 16)) * 64 + lane;
        short8 bfr[16];
#pragma unroll
        for (int ct = 0; ct < 16; ++ct) bfr[ct] = bp[ct * 64];
#pragma unroll
        for (int ct = 0; ct < 16; ++ct)
            acc[ct] = __builtin_amdgcn_mfma_f32_16x16x32_bf16(a, bfr[ct], acc[ct], 0, 0, 0);
    }

    // ---- epilogue in 8 chunks of 2 rows via per-wave V scratch ----
    // C/D layout: lane q=lane>>4 holds rows q*4+r (r=0..3), col = ct*16 + (lane&15).
    // chunk c covers tile-rel rows 2c, 2c+1 (owner q0 = c>>1, r0 = (2c)&3).
#pragma unroll
    for (int c = 0; c < 8; ++c) {
        const int q0 = c >> 1;
        const int r0 = (2 * c) & 3;
        __syncthreads();
        if (q == q0) {
#pragma unroll
            for (int ct = 0; ct < 16; ++ct) {
                Vscr[w][0][ct * 16 + m] = acc[ct][r0];
                Vscr[w][1][ct * 16 + m] = acc[ct][r0 + 1];
            }
        }
        __syncthreads();
#pragma unroll
        for (int rr = 0; rr < 2; ++rr) {
            const int rl = w16 + 2 * c + rr;   // V row / hn prev row; token t = T0 + rl
            const float4 vv = *(const float4*)&Vscr[w][rr][lane * 4];
            const float4 hp = *(const float4*)&hnf[rl * 260 + lane * 4];
            const float4 hc = *(const float4*)&hnf[(rl + 1) * 260 + lane * 4];
            float part = (vv.x + hp.x) * hc.x + (vv.y + hp.y) * hc.y
                       + (vv.z + hp.z) * hc.z + (vv.w + hp.w) * hc.w;
#pragma unroll
            for (int mm = 32; mm >= 1; mm >>= 1) part += __shfl_xor(part, mm);
            if (lane == 0) {
                const int t = T0 + rl;
                const int l = t & (L_SEQ - 1);
                float p;
                if (l == 0) {
                    p = 1.0f;
                } else {
                    p = (1.0f - part) * 0.5f;
                    p = fminf(fmaxf(p, 0.0f), 1.0f);
                }
                p = fminf(fmaxf(p, EPS_F), 1.0f - EPS_F);
                float u = noise[t];
                u = fminf(fmaxf(u, EPS_F), 1.0f - EPS_F);
                const float z = ((logf(p) - log1pf(-p)) + logf(u)) - log1pf(-u);
                hard[t] = (z > 0.0f) ? (unsigned char)1 : (unsigned char)0;
            }
        }
    }
}

// ---------------------- K4: per-row length, forced boundary, scan -> starts, n_b, mask
__global__ void k_scan(const float* __restrict__ mask, const unsigned char* __restrict__ hard,
                       int* __restrict__ starts, int* __restrict__ nb_arr,
                       int* __restrict__ len_arr, float* __restrict__ out_short) {
    __shared__ int sc[256];
    __shared__ int s_len;
    const int b = blockIdx.x, tid = threadIdx.x;
    const int base = b * L_SEQ;

    // row length = sum(mask) (contiguous prefix of ones)
    int cnt = 0;
    const float4* m4 = (const float4*)(mask + base);
    for (int i = tid; i < L_SEQ / 4; i += 256) {
        const float4 v = m4[i];
        cnt += (v.x != 0.0f) + (v.y != 0.0f) + (v.z != 0.0f) + (v.w != 0.0f);
    }
    sc[tid] = cnt;
    __syncthreads();
    for (int ofs = 128; ofs > 0; ofs >>= 1) {
        if (tid < ofs) sc[tid] += sc[tid + ofs];
        __syncthreads();
    }
    if (tid == 0) s_len = sc[0];
    __syncthreads();
    const int len = s_len;

    // adjusted hard bits for this thread's contiguous chunk [32*tid, 32*tid+32)
    const int i0 = tid * 32;
    unsigned int bits = 0;
    int c = 0;
#pragma unroll
    for (int j = 0; j < 32; ++j) {
        const int i = i0 + j;
        int h = (i < len) ? (int)hard[base + i] : 0;
        if (len < L_SEQ && i == len - 1) h = 1;  // forced boundary at last real token
        bits |= (unsigned int)h << j;
        c += h;
    }
    __syncthreads();
    sc[tid] = c;
    __syncthreads();
    // inclusive Hillis-Steele scan over 256 thread counts
    for (int ofs = 1; ofs < 256; ofs <<= 1) {
        const int v = (tid >= ofs) ? sc[tid - ofs] : 0;
        __syncthreads();
        sc[tid] += v;
        __syncthreads();
    }
    const int off = sc[tid] - c;
    const int nb = sc[255];

    int run = off;
#pragma unroll
    for (int j = 0; j < 32; ++j)
        if ((bits >> j) & 1u) { starts[base + run] = i0 + j; ++run; }

    if (tid == 0) { nb_arr[b] = nb; len_arr[b] = len; }

    for (int i = tid; i < L_SEQ; i += 256) out_short[base + i] = (i < nb) ? 1.0f : 0.0f;
}

// --------------------------------------------- K5: one wave per segment, mean-pool
__global__ __launch_bounds__(256) void k_pool(
    const float* __restrict__ hidden, const int* __restrict__ starts,
    const int* __restrict__ nb_arr, const int* __restrict__ len_arr,
    float* __restrict__ pooled) {
    const int tid  = threadIdx.x;
    const int lane = tid & 63;
    const int wid  = blockIdx.x * 4 + (tid >> 6);
    const int b    = wid >> 13;       // / 8192
    const int s    = wid & (L_SEQ - 1);
    const int nb   = nb_arr[b];

    float4 res = {0.f, 0.f, 0.f, 0.f};
    if (s < nb) {
        const int start = (s == 0) ? 0 : starts[b * L_SEQ + s];
        const int end   = (s + 1 < nb) ? starts[b * L_SEQ + s + 1] : len_arr[b];
        float4 acc = {0.f, 0.f, 0.f, 0.f};
        for (int t = start; t < end; ++t) {
            const float4 v = ((const float4*)hidden)[(b * L_SEQ + t) * 64 + lane];
            acc.x += v.x; acc.y += v.y; acc.z += v.z; acc.w += v.w;
        }
        const float cntf = (float)(end - start);
        res.x = acc.x / cntf; res.y = acc.y / cntf; res.z = acc.z / cntf; res.w = acc.w / cntf;
    }
    ((float4*)pooled)[(size_t)wid * 64 + lane] = res;
}

// ---------------------------------------------------- K6: scalars (loss via lgamma)
__global__ void k_final(const int* __restrict__ nb_arr, const int* __restrict__ len_arr,
                        float* __restrict__ out_scal) {
    if (threadIdx.x == 0) {
        int nb = 0, ln = 0;
        for (int b = 0; b < B_BATCH; ++b) { nb += nb_arr[b]; ln += len_arr[b]; }
        const double k = (double)nb, n = (double)ln;
        const double logp = lgamma(n + 1.0) - lgamma(k + 1.0) - lgamma(n - k + 1.0)
                            + k * log(0.2) + (n - k) * log(0.8);
        const double loss = -logp / n;
        out_scal[0] = (float)loss;
        out_scal[1] = (float)nb;
        out_scal[2] = (float)ln;
    }
}

extern "C" void kernel_launch(void* const* d_in, const int* in_sizes, int n_in,
                              void* d_out, int out_size, void* d_ws, size_t ws_size,
                              hipStream_t stream) {
    const float* hidden = (const float*)d_in[0];
    const float* Wq     = (const float*)d_in[1];
    const float* Wk     = (const float*)d_in[2];
    const float* noise  = (const float*)d_in[3];
    const float* mask   = (const float*)d_in[4];
    float* out = (float*)d_out;
    char* ws = (char*)d_ws;

    float*          M      = (float*)(ws);                 // dead after k_packB
    int*            starts = (int*)(ws);                   // reuses M region (k_scan onward)
    unsigned short* Bpack  = (unsigned short*)(ws + 262144);
    unsigned char*  hard   = (unsigned char*)(ws + 524288);
    int*            nb_arr = (int*)(ws + 589824);
    int*            len_arr= (int*)(ws + 589856);

    float* pooled = out;
    float* scal   = out + (size_t)BL * D_DIM;
    float* shortm = scal + 3;

    k_matM   <<<dim3(16, 16), dim3(16, 16), 0, stream>>>(Wq, Wk, M);
    k_packB  <<<256, 64, 0, stream>>>(M, Bpack);
    k_cosmfma<<<BL / 64, 256, 0, stream>>>(hidden, Bpack, noise, hard);
    k_scan   <<<B_BATCH, 256, 0, stream>>>(mask, hard, starts, nb_arr, len_arr, shortm);
    k_pool   <<<BL / 4, 256, 0, stream>>>(hidden, starts, nb_arr, len_arr, pooled);
    k_final  <<<1, 64, 0, stream>>>(nb_arr, len_arr, scal);
}

// Round 6
// 250.392 us; speedup vs baseline: 1.3952x; 1.2106x over previous
//
#include <hip/hip_runtime.h>
#include <hip/hip_bf16.h>
#include <math.h>

#define L_SEQ 8192
#define B_BATCH 8
#define D_DIM 256
#define BL (B_BATCH * L_SEQ)
#define EPS_F 1.1920929e-07f

typedef __attribute__((ext_vector_type(8))) short short8;
typedef __attribute__((ext_vector_type(4))) float f32x4;

// ws layout (bytes):
//   [0,       262144)  M fp32 256x256  (dead after k_packB)  ∪ starts int32 BL (k_scan+)
//   [262144,  524288)  Bpack bf16: 2 segs (M1,M2) x 8 k8 x 16 ct fragments x 64 lanes x 8
//   [524288,  589824)  hard  uint8  BL
//   [589824,  589856)  n_b   int32  8
//   [589856,  589888)  len   int32  8

__device__ inline unsigned short f2bf(float x) {
    __hip_bfloat16 b = __float2bfloat16(x);
    return *(unsigned short*)&b;
}
__device__ inline float bf2f(unsigned short u) {
    __hip_bfloat16 b = *(__hip_bfloat16*)&u;
    return __bfloat162float(b);
}

// ---------------------------------------------------------------- K1: M = Wq^T * Wk
__global__ void k_matM(const float* __restrict__ Wq, const float* __restrict__ Wk,
                       float* __restrict__ M) {
    __shared__ float Aq[16][17];
    __shared__ float Ak[16][17];
    const int tx = threadIdx.x, ty = threadIdx.y;
    const int d  = blockIdx.y * 16 + ty;   // row of M
    const int dp = blockIdx.x * 16 + tx;   // col of M
    float acc = 0.f;
    for (int e0 = 0; e0 < 256; e0 += 16) {
        Aq[ty][tx] = Wq[(e0 + ty) * 256 + blockIdx.y * 16 + tx];
        Ak[ty][tx] = Wk[(e0 + ty) * 256 + blockIdx.x * 16 + tx];
        __syncthreads();
#pragma unroll
        for (int i = 0; i < 16; ++i) acc += Aq[i][ty] * Ak[i][tx];
        __syncthreads();
    }
    M[d * 256 + dp] = acc;
}

// ------------------------- K2: pack (M - I) into bf16 hi/lo MFMA B-fragment layout
// B-frag (16x16x32 bf16): lane holds B[k = k8*32 + (lane>>4)*8 + j][n = ct*16 + (lane&15)]
// Bpack[seg][k8][ct] fragment = 64 lanes x 8 bf16 (1 KB), lane-linear (coalesced b128).
__global__ void k_packB(const float* __restrict__ M, unsigned short* __restrict__ Bpack) {
    const int f    = blockIdx.x;          // 0..255
    const int seg  = f >> 7;              // 0: hi(M1), 1: lo(M2)
    const int k8   = (f >> 4) & 7;
    const int ct   = f & 15;
    const int lane = threadIdx.x;         // 0..63
    const int q    = lane >> 4;
    const int n    = ct * 16 + (lane & 15);
    unsigned short v[8];
#pragma unroll
    for (int j = 0; j < 8; ++j) {
        const int k = k8 * 32 + q * 8 + j;
        const float Mm = M[k * 256 + n] - (k == n ? 1.0f : 0.0f);
        const unsigned short h = f2bf(Mm);
        v[j] = seg ? f2bf(Mm - bf2f(h)) : h;
    }
    unsigned short* dst = Bpack + (size_t)f * 512 + lane * 8;
#pragma unroll
    for (int j = 0; j < 8; ++j) dst[j] = v[j];
}

// ------------------------------ K3: normalize + MFMA correction GEMM + cos + hard bit
// Block = 256 thr = 4 waves, 64 output tokens [T0, T0+64). hn fp32 rows i <-> token T0-1+i.
// cos(t) = hn_{t-1}.hn_t (exact fp32) + hn_{t-1}^T (M-I) hn_t (bf16 hi/lo 3-term MFMA).
// A-fragments (h,l) are rebuilt per K-strip from hnf (2 ds_read_b128 + converts) to keep
// register pressure low (R5's persistent-fragment version spilled 64 VGPRs to scratch).
// Strip pass 1: M1 strip feeds BOTH h and l MFMAs (B loaded once). Pass 2: M2 with h.
__global__ __launch_bounds__(256, 2) void k_cosmfma(
    const float* __restrict__ hidden, const unsigned short* __restrict__ Bpack,
    const float* __restrict__ noise, unsigned char* __restrict__ hard) {
    __shared__ __attribute__((aligned(16))) float hnf[65 * 260];     // 67,600 B
    __shared__ __attribute__((aligned(16))) float Vscr[4][2][256];   //  8,192 B

    const int tid  = threadIdx.x;
    const int lane = tid & 63;
    const int w    = tid >> 6;        // wave 0..3
    const int T0   = blockIdx.x * 64;

    // ---- stage + normalize 65 fp32 rows into LDS ----
    for (int i = w; i < 65; i += 4) {
        int tok = T0 - 1 + i;
        tok = tok < 0 ? 0 : tok;
        const float4 v = ((const float4*)hidden)[(size_t)tok * 64 + lane];
        float ss = v.x * v.x + v.y * v.y + v.z * v.z + v.w * v.w;
#pragma unroll
        for (int m = 32; m >= 1; m >>= 1) ss += __shfl_xor(ss, m);
        const float den = fmaxf(sqrtf(ss), 1e-12f);
        float4 h4;
        h4.x = v.x / den; h4.y = v.y / den; h4.z = v.z / den; h4.w = v.w / den;
        *(float4*)&hnf[i * 260 + lane * 4] = h4;
    }
    __syncthreads();

    // lane holds A[m = lane&15][k = k8*32 + (lane>>4)*8 + j]; A row m <-> hnf row w*16+m
    const int m = lane & 15, q = lane >> 4;
    const int w16 = w * 16;
    const float* __restrict__ arow = &hnf[(w16 + m) * 260 + q * 8];

    const short8* __restrict__ B8 = (const short8*)Bpack;
    f32x4 acc[16];
#pragma unroll
    for (int ct = 0; ct < 16; ++ct) { f32x4 z = {0.f, 0.f, 0.f, 0.f}; acc[ct] = z; }

    // ---- pass 1: 8 strips of M1; each strip feeds h-MFMA and l-MFMA ----
#pragma unroll 1
    for (int k8 = 0; k8 < 8; ++k8) {
        const short8* bp = B8 + (k8 * 16) * 64 + lane;
        short8 bfr[16];
#pragma unroll
        for (int ct = 0; ct < 16; ++ct) bfr[ct] = bp[ct * 64];

        const float4 x0 = *(const float4*)(arow + k8 * 32);
        const float4 x1 = *(const float4*)(arow + k8 * 32 + 4);
        const float xs[8] = {x0.x, x0.y, x0.z, x0.w, x1.x, x1.y, x1.z, x1.w};
        short8 hv, lv;
#pragma unroll
        for (int j = 0; j < 8; ++j) {
            const unsigned short hh = f2bf(xs[j]);
            hv[j] = (short)hh;
            lv[j] = (short)f2bf(xs[j] - bf2f(hh));
        }
#pragma unroll
        for (int ct = 0; ct < 16; ++ct)
            acc[ct] = __builtin_amdgcn_mfma_f32_16x16x32_bf16(hv, bfr[ct], acc[ct], 0, 0, 0);
#pragma unroll
        for (int ct = 0; ct < 16; ++ct)
            acc[ct] = __builtin_amdgcn_mfma_f32_16x16x32_bf16(lv, bfr[ct], acc[ct], 0, 0, 0);
    }

    // ---- pass 2: 8 strips of M2 with h-fragment ----
#pragma unroll 1
    for (int k8 = 0; k8 < 8; ++k8) {
        const short8* bp = B8 + (128 + k8 * 16) * 64 + lane;
        short8 bfr[16];
#pragma unroll
        for (int ct = 0; ct < 16; ++ct) bfr[ct] = bp[ct * 64];

        const float4 x0 = *(const float4*)(arow + k8 * 32);
        const float4 x1 = *(const float4*)(arow + k8 * 32 + 4);
        const float xs[8] = {x0.x, x0.y, x0.z, x0.w, x1.x, x1.y, x1.z, x1.w};
        short8 hv;
#pragma unroll
        for (int j = 0; j < 8; ++j) hv[j] = (short)f2bf(xs[j]);
#pragma unroll
        for (int ct = 0; ct < 16; ++ct)
            acc[ct] = __builtin_amdgcn_mfma_f32_16x16x32_bf16(hv, bfr[ct], acc[ct], 0, 0, 0);
    }

    // ---- epilogue in 8 chunks of 2 rows via per-wave V scratch ----
    // C/D layout: lane q=lane>>4 holds rows q*4+r (r=0..3), col = ct*16 + (lane&15).
#pragma unroll 1
    for (int c = 0; c < 8; ++c) {
        const int q0 = c >> 1;
        const int r0 = (2 * c) & 3;
        __syncthreads();
        if (q == q0) {
#pragma unroll
            for (int ct = 0; ct < 16; ++ct) {
                Vscr[w][0][ct * 16 + m] = acc[ct][r0];
                Vscr[w][1][ct * 16 + m] = acc[ct][r0 + 1];
            }
        }
        __syncthreads();
#pragma unroll
        for (int rr = 0; rr < 2; ++rr) {
            const int rl = w16 + 2 * c + rr;   // V row / hn prev row; token t = T0 + rl
            const float4 vv = *(const float4*)&Vscr[w][rr][lane * 4];
            const float4 hp = *(const float4*)&hnf[rl * 260 + lane * 4];
            const float4 hc = *(const float4*)&hnf[(rl + 1) * 260 + lane * 4];
            float part = (vv.x + hp.x) * hc.x + (vv.y + hp.y) * hc.y
                       + (vv.z + hp.z) * hc.z + (vv.w + hp.w) * hc.w;
#pragma unroll
            for (int mm = 32; mm >= 1; mm >>= 1) part += __shfl_xor(part, mm);
            if (lane == 0) {
                const int t = T0 + rl;
                const int l = t & (L_SEQ - 1);
                float p;
                if (l == 0) {
                    p = 1.0f;
                } else {
                    p = (1.0f - part) * 0.5f;
                    p = fminf(fmaxf(p, 0.0f), 1.0f);
                }
                p = fminf(fmaxf(p, EPS_F), 1.0f - EPS_F);
                float u = noise[t];
                u = fminf(fmaxf(u, EPS_F), 1.0f - EPS_F);
                const float z = ((logf(p) - log1pf(-p)) + logf(u)) - log1pf(-u);
                hard[t] = (z > 0.0f) ? (unsigned char)1 : (unsigned char)0;
            }
        }
    }
}

// ---------------------- K4: per-row length, forced boundary, scan -> starts, n_b, mask
__global__ void k_scan(const float* __restrict__ mask, const unsigned char* __restrict__ hard,
                       int* __restrict__ starts, int* __restrict__ nb_arr,
                       int* __restrict__ len_arr, float* __restrict__ out_short) {
    __shared__ int sc[256];
    __shared__ int s_len;
    const int b = blockIdx.x, tid = threadIdx.x;
    const int base = b * L_SEQ;

    // row length = sum(mask) (contiguous prefix of ones)
    int cnt = 0;
    const float4* m4 = (const float4*)(mask + base);
    for (int i = tid; i < L_SEQ / 4; i += 256) {
        const float4 v = m4[i];
        cnt += (v.x != 0.0f) + (v.y != 0.0f) + (v.z != 0.0f) + (v.w != 0.0f);
    }
    sc[tid] = cnt;
    __syncthreads();
    for (int ofs = 128; ofs > 0; ofs >>= 1) {
        if (tid < ofs) sc[tid] += sc[tid + ofs];
        __syncthreads();
    }
    if (tid == 0) s_len = sc[0];
    __syncthreads();
    const int len = s_len;

    // adjusted hard bits for this thread's contiguous chunk [32*tid, 32*tid+32)
    const int i0 = tid * 32;
    unsigned int bits = 0;
    int c = 0;
#pragma unroll
    for (int j = 0; j < 32; ++j) {
        const int i = i0 + j;
        int h = (i < len) ? (int)hard[base + i] : 0;
        if (len < L_SEQ && i == len - 1) h = 1;  // forced boundary at last real token
        bits |= (unsigned int)h << j;
        c += h;
    }
    __syncthreads();
    sc[tid] = c;
    __syncthreads();
    // inclusive Hillis-Steele scan over 256 thread counts
    for (int ofs = 1; ofs < 256; ofs <<= 1) {
        const int v = (tid >= ofs) ? sc[tid - ofs] : 0;
        __syncthreads();
        sc[tid] += v;
        __syncthreads();
    }
    const int off = sc[tid] - c;
    const int nb = sc[255];

    int run = off;
#pragma unroll
    for (int j = 0; j < 32; ++j)
        if ((bits >> j) & 1u) { starts[base + run] = i0 + j; ++run; }

    if (tid == 0) { nb_arr[b] = nb; len_arr[b] = len; }

    for (int i = tid; i < L_SEQ; i += 256) out_short[base + i] = (i < nb) ? 1.0f : 0.0f;
}

// --------------------------------------------- K5: one wave per segment, mean-pool
__global__ __launch_bounds__(256) void k_pool(
    const float* __restrict__ hidden, const int* __restrict__ starts,
    const int* __restrict__ nb_arr, const int* __restrict__ len_arr,
    float* __restrict__ pooled) {
    const int tid  = threadIdx.x;
    const int lane = tid & 63;
    const int wid  = blockIdx.x * 4 + (tid >> 6);
    const int b    = wid >> 13;       // / 8192
    const int s    = wid & (L_SEQ - 1);
    const int nb   = nb_arr[b];

    float4 res = {0.f, 0.f, 0.f, 0.f};
    if (s < nb) {
        const int start = (s == 0) ? 0 : starts[b * L_SEQ + s];
        const int end   = (s + 1 < nb) ? starts[b * L_SEQ + s + 1] : len_arr[b];
        float4 acc = {0.f, 0.f, 0.f, 0.f};
        for (int t = start; t < end; ++t) {
            const float4 v = ((const float4*)hidden)[(b * L_SEQ + t) * 64 + lane];
            acc.x += v.x; acc.y += v.y; acc.z += v.z; acc.w += v.w;
        }
        const float cntf = (float)(end - start);
        res.x = acc.x / cntf; res.y = acc.y / cntf; res.z = acc.z / cntf; res.w = acc.w / cntf;
    }
    ((float4*)pooled)[(size_t)wid * 64 + lane] = res;
}

// ---------------------------------------------------- K6: scalars (loss via lgamma)
__global__ void k_final(const int* __restrict__ nb_arr, const int* __restrict__ len_arr,
                        float* __restrict__ out_scal) {
    if (threadIdx.x == 0) {
        int nb = 0, ln = 0;
        for (int b = 0; b < B_BATCH; ++b) { nb += nb_arr[b]; ln += len_arr[b]; }
        const double k = (double)nb, n = (double)ln;
        const double logp = lgamma(n + 1.0) - lgamma(k + 1.0) - lgamma(n - k + 1.0)
                            + k * log(0.2) + (n - k) * log(0.8);
        const double loss = -logp / n;
        out_scal[0] = (float)loss;
        out_scal[1] = (float)nb;
        out_scal[2] = (float)ln;
    }
}

extern "C" void kernel_launch(void* const* d_in, const int* in_sizes, int n_in,
                              void* d_out, int out_size, void* d_ws, size_t ws_size,
                              hipStream_t stream) {
    const float* hidden = (const float*)d_in[0];
    const float* Wq     = (const float*)d_in[1];
    const float* Wk     = (const float*)d_in[2];
    const float* noise  = (const float*)d_in[3];
    const float* mask   = (const float*)d_in[4];
    float* out = (float*)d_out;
    char* ws = (char*)d_ws;

    float*          M      = (float*)(ws);                 // dead after k_packB
    int*            starts = (int*)(ws);                   // reuses M region (k_scan onward)
    unsigned short* Bpack  = (unsigned short*)(ws + 262144);
    unsigned char*  hard   = (unsigned char*)(ws + 524288);
    int*            nb_arr = (int*)(ws + 589824);
    int*            len_arr= (int*)(ws + 589856);

    float* pooled = out;
    float* scal   = out + (size_t)BL * D_DIM;
    float* shortm = scal + 3;

    k_matM   <<<dim3(16, 16), dim3(16, 16), 0, stream>>>(Wq, Wk, M);
    k_packB  <<<256, 64, 0, stream>>>(M, Bpack);
    k_cosmfma<<<BL / 64, 256, 0, stream>>>(hidden, Bpack, noise, hard);
    k_scan   <<<B_BATCH, 256, 0, stream>>>(mask, hard, starts, nb_arr, len_arr, shortm);
    k_pool   <<<BL / 4, 256, 0, stream>>>(hidden, starts, nb_arr, len_arr, pooled);
    k_final  <<<1, 64, 0, stream>>>(nb_arr, len_arr, scal);
}